// Round 7
// baseline (267.092 us; speedup 1.0000x reference)
//
#include <hip/hip_runtime.h>

// Causal MHA fwd: B=2, N=2048, H=16, D=64. fp32 in / fp32 out.
// Tensors flat row-major (B*H, N, 64). Flash attention, 32x32 MFMA.
//
// Round 18: producer/consumer wave specialization + k-split consumers.
//  - R17 evidence: VGPR=76 < staged(32)+persistent(48) -> staged loads were
//    ALWAYS sunk to the write point (sched_barrier(0) can't stop cross-BB
//    sinking) -> every iteration serialized a raw L2/HBM latency. This was
//    true in every prior round and explains structure-insensitivity at
//    ~50us.
//  - Fix 1: 2 producer waves per block own ALL global->LDS staging. Their
//    vmcnt stall overlaps consumer compute across the barrier interval by
//    construction; consumers never touch global memory in the loop.
//  - Fix 2: 8 consumer waves = 4 q-groups x 2 key-halves (k-split). With
//    exp2-direct softmax (no running max) l and o combine LINEARLY, so
//    key-halves are exact partial sums, combined once via LDS at epilogue.
//    Halves each wave's per-iteration dependency chain, doubles resident
//    compute waves (20 waves/CU at 2 blocks/CU).
//  - Wave (qw,kh): itl = 2Tq + ((qw-kh)>>1); triangular diagonal iff
//    (qw-kh) even, at it==itl, mask: (r&3)+8*(r>>2)+4h > q31 (verified
//    chunk coverage exact+disjoint). nt = 2Tq+2 unchanged.
//  - setprio(1) wraps consumer compute only: producers run at prio 0 ->
//    scheduler favors MFMA waves (true role diversity now).
// Verified carried-over pieces: bf16 LDS layouts (KP/VP=72, 0 bank
// conflicts), MK_PA permlane transform, raw v_exp_f32, pair-balanced
// T-map, XCD-friendly bh decode.

typedef short  short8v __attribute__((ext_vector_type(8)));
typedef float  float8v __attribute__((ext_vector_type(8)));
typedef float  f32x16  __attribute__((ext_vector_type(16)));

#define NQ 2048
#define DD 64
#define KT 64          // keys per iteration
#define KP 72          // K LDS row pitch (bf16 elts), 144B
#define VP 72          // V^T LDS row pitch

#define Z16 ((f32x16){0.f,0.f,0.f,0.f,0.f,0.f,0.f,0.f,0.f,0.f,0.f,0.f,0.f,0.f,0.f,0.f})
#define mfma32 __builtin_amdgcn_mfma_f32_32x32x16_bf16

union U4 { unsigned int u[4]; short8v s; };

// truncating pack: two f32 -> two bf16 (lo -> low half)
static __device__ __forceinline__ unsigned int pktr(float lo, float hi) {
    return __builtin_amdgcn_perm(__builtin_bit_cast(unsigned int, hi),
                                 __builtin_bit_cast(unsigned int, lo),
                                 0x07060302);
}
// round-half-up pack — used for Q (once per wave)
static __device__ __forceinline__ unsigned int pkrn(float lo, float hi) {
    unsigned int a = __builtin_bit_cast(unsigned int, hi) + 0x8000u;
    unsigned int b = __builtin_bit_cast(unsigned int, lo) + 0x8000u;
    return __builtin_amdgcn_perm(a, b, 0x07060302);
}
// RNE pack via HW instruction (P values)
static __device__ __forceinline__ unsigned int cvtpk(float lo, float hi) {
    unsigned int d;
    asm("v_cvt_pk_bf16_f32 %0, %1, %2" : "=v"(d) : "v"(lo), "v"(hi));
    return d;
}
// raw HW exp2 (no OCML guard); exp2(-3e38) = 0 handles the causal mask
static __device__ __forceinline__ float fexp2(float x) {
    float y;
    asm("v_exp_f32 %0, %1" : "=v"(y) : "v"(x));
    return y;
}

// Build one PA fragment (A-operand slice: P[q][16s'+8h+j], j=0..7)
// from sT regs B..B+7. After swap: P0,P1,P2,P3 = words w0..w3. (verified R16)
#define MK_PA(dst, S, B)                                                     \
    {                                                                        \
        unsigned int P0 = cvtpk(S[(B) + 0], S[(B) + 1]);                     \
        unsigned int P1 = cvtpk(S[(B) + 2], S[(B) + 3]);                     \
        unsigned int P2 = cvtpk(S[(B) + 4], S[(B) + 5]);                     \
        unsigned int P3 = cvtpk(S[(B) + 6], S[(B) + 7]);                     \
        asm("v_permlane32_swap_b32 %0, %1" : "+v"(P0), "+v"(P2));            \
        asm("v_permlane32_swap_b32 %0, %1" : "+v"(P1), "+v"(P3));            \
        U4 w_;                                                               \
        w_.u[0] = P0; w_.u[1] = P1; w_.u[2] = P2; w_.u[3] = P3;              \
        dst = w_.s;                                                          \
    }

__global__ __launch_bounds__(640, 5) void mha_fwd_kernel(
    const float* __restrict__ Kg,
    const float* __restrict__ Qg,
    const float* __restrict__ Vg,
    float* __restrict__ Og)
{
    // single shared block: [Klds buf0|buf1][Vt buf0|buf1]; reused as f32
    // scratch for the kh-combine epilogue. 36864 B total.
    __shared__ __align__(16) unsigned short SM[2 * KT * KP + 2 * DD * VP];
#define KL(c) (&SM[(c) * (KT * KP)])
#define VT(c) (&SM[2 * (KT * KP) + (c) * (DD * VP)])

    const int t    = threadIdx.x;
    const int lane = t & 63;
    const int wave = t >> 6;       // 0..9
    const int q31  = lane & 31;
    const int h    = lane >> 5;

    // 512 blocks: b&255 -> (bh, j); b>>8 picks heavy (15-j) vs light (j)
    // q-tile. CU gets blocks b and b+256: iteration sum = 36 (balanced).
    const int b   = blockIdx.x;
    const int rb  = b & 255;
    const int bh  = rb & 31;
    const int jj  = rb >> 5;                   // 0..7
    const int Tq  = (b >> 8) ? jj : (15 - jj); // q-tile index, 128 rows
    const int nt  = 2 * Tq + 2;                // block k-iterations

    const bool producer = (wave >= 8);
    const int  qw = wave & 3;                  // consumer q-group
    const int  kh = (wave >> 2) & 1;           // consumer key-half
    const int  q0 = Tq * 128 + qw * 32;        // consumer's 32 q rows
    // last compute iteration; diagonal (triangular mask) iff (qw-kh) even
    const int  itl  = producer ? -1 : (2 * Tq + ((qw - kh) >> 1));
    const bool hasd = !producer && (((qw - kh) & 1) == 0);

    const size_t base = (size_t)bh * NQ * DD;
    const float* Qp = Qg + base;
    const float* Kp = Kg + base;
    const float* Vp = Vg + base;
    float*       Op = Og + base;

    const float sscale = 0.125f * 1.4426950408889634f;  // 1/sqrt(64)*log2(e)

    // producer staging roles (128 lanes):
    //   K: lane pt -> row kr = pt>>1, cols kc..kc+31 (32 consecutive f32)
    //   V^T: lane pt -> d-row vd = pt&63, keys vg..vg+31
    const int pt = t - 512;
    const int kr = pt >> 1, kc = (pt & 1) * 32;
    const int vd = pt & 63, vg = ((pt >> 6) & 1) * 32;

    // ---- consumer: Q fragments (B-operand), scale folded, RNE pack ----
    short8v qf[4];
    if (!producer) {
#pragma unroll
        for (int s = 0; s < 4; ++s) {
            float8v a = *(const float8v*)(Qp + (size_t)(q0 + q31) * DD + s * 16 + h * 8);
            U4 w;
#pragma unroll
            for (int i = 0; i < 4; ++i)
                w.u[i] = pkrn(a[2 * i] * sscale, a[2 * i + 1] * sscale);
            qf[s] = w.s;
        }
    }

    float  l_i = 0.0f;
    f32x16 o0 = Z16, o1 = Z16;

    // ---- prologue: producers stage tile 0 into buffer 0 ----
    if (producer) {
        float8v ka[4];
        float   vr[32];
#pragma unroll
        for (int i = 0; i < 4; ++i)
            ka[i] = *(const float8v*)(Kp + (size_t)kr * DD + kc + i * 8);
#pragma unroll
        for (int i = 0; i < 32; ++i)
            vr[i] = Vp[(size_t)(vg + i) * DD + vd];
        U4 w;
#pragma unroll
        for (int i = 0; i < 4; ++i) {
#pragma unroll
            for (int jx = 0; jx < 4; ++jx)
                w.u[jx] = pktr(ka[i][2 * jx], ka[i][2 * jx + 1]);
            *(short8v*)&KL(0)[kr * KP + kc + i * 8] = w.s;
        }
#pragma unroll
        for (int i = 0; i < 4; ++i) {
#pragma unroll
            for (int jx = 0; jx < 4; ++jx)
                w.u[jx] = pktr(vr[8 * i + 2 * jx], vr[8 * i + 2 * jx + 1]);
            *(short8v*)&VT(0)[vd * VP + vg + i * 8] = w.s;
        }
    }
    __syncthreads();

    for (int it = 0; it < nt; ++it) {
        const int cur = it & 1;

        if (producer) {
            // ---- stage tile it+1 into buf[cur^1]; vmcnt stall lives HERE,
            //      overlapped with consumer compute in this interval ----
            if (it + 1 < nt) {
                const int nkb = (it + 1) * KT;
                float8v ka[4];
                float   vr[32];
#pragma unroll
                for (int i = 0; i < 4; ++i)
                    ka[i] = *(const float8v*)(Kp + (size_t)(nkb + kr) * DD + kc + i * 8);
#pragma unroll
                for (int i = 0; i < 32; ++i)
                    vr[i] = Vp[(size_t)(nkb + vg + i) * DD + vd];
                U4 w;
#pragma unroll
                for (int i = 0; i < 4; ++i) {
#pragma unroll
                    for (int jx = 0; jx < 4; ++jx)
                        w.u[jx] = pktr(ka[i][2 * jx], ka[i][2 * jx + 1]);
                    *(short8v*)&KL(cur ^ 1)[kr * KP + kc + i * 8] = w.s;
                }
#pragma unroll
                for (int i = 0; i < 4; ++i) {
#pragma unroll
                    for (int jx = 0; jx < 4; ++jx)
                        w.u[jx] = pktr(vr[8 * i + 2 * jx], vr[8 * i + 2 * jx + 1]);
                    *(short8v*)&VT(cur ^ 1)[vd * VP + vg + i * 8] = w.s;
                }
            }
        } else if (it <= itl) {
            // ---- consumer: one 32-key tile (its kh half) ----
            __builtin_amdgcn_s_setprio(1);

            f32x16 sT = Z16;
#pragma unroll
            for (int s = 0; s < 4; ++s) {
                short8v kf = *(const short8v*)&KL(cur)[(kh * 32 + q31) * KP + s * 16 + h * 8];
                sT = mfma32(kf, qf[s], sT, 0, 0, 0);
            }

            if (hasd && it == itl) {
#pragma unroll
                for (int r = 0; r < 16; ++r) {
                    const int kcst = (r & 3) + 8 * (r >> 2);
                    if (kcst + 4 * h > q31) sT[r] = -3.0e38f;
                }
            }

#pragma unroll
            for (int r = 0; r < 16; ++r) sT[r] = fexp2(sT[r]);
            l_i += (((sT[0] + sT[1]) + (sT[2] + sT[3])) +
                    ((sT[4] + sT[5]) + (sT[6] + sT[7]))) +
                   (((sT[8] + sT[9]) + (sT[10] + sT[11])) +
                    ((sT[12] + sT[13]) + (sT[14] + sT[15])));

            short8v pa0, pa1;
            MK_PA(pa0, sT, 0);
            MK_PA(pa1, sT, 8);

            const unsigned short* vb = VT(cur);
            short8v v00 = *(const short8v*)&vb[q31 * VP        + (2 * kh)     * 16 + h * 8];
            short8v v01 = *(const short8v*)&vb[q31 * VP        + (2 * kh + 1) * 16 + h * 8];
            short8v v10 = *(const short8v*)&vb[(32 + q31) * VP + (2 * kh)     * 16 + h * 8];
            short8v v11 = *(const short8v*)&vb[(32 + q31) * VP + (2 * kh + 1) * 16 + h * 8];
            o0 = mfma32(pa0, v00, o0, 0, 0, 0);
            o0 = mfma32(pa1, v01, o0, 0, 0, 0);
            o1 = mfma32(pa0, v10, o1, 0, 0, 0);
            o1 = mfma32(pa1, v11, o1, 0, 0, 0);

            __builtin_amdgcn_s_setprio(0);
        }

        __syncthreads();  // buf[cur^1] staged; buf[cur] reads drained
    }

    // ---- epilogue: combine kh halves via LDS (linear: exp2-direct) ----
    const float rs0 = l_i + __shfl_xor(l_i, 32);
    float* smf = (float*)SM;
    if (!producer && kh == 1) {
        float* dst = smf + (qw * 64 + lane) * 33;
#pragma unroll
        for (int r = 0; r < 16; ++r) { dst[r] = o0[r]; dst[16 + r] = o1[r]; }
        dst[32] = rs0;
    }
    __syncthreads();
    if (!producer && kh == 0) {
        const float* src = smf + (qw * 64 + lane) * 33;
        float rs = rs0 + src[32];
        f32x16 f0 = o0, f1 = o1;
#pragma unroll
        for (int r = 0; r < 16; ++r) { f0[r] += src[r]; f1[r] += src[16 + r]; }
        const float rinv = 1.0f / rs;
#pragma unroll
        for (int r = 0; r < 16; ++r) {
            const int   qrow = (r & 3) + 8 * (r >> 2) + 4 * h;
            const float lv   = __shfl(rinv, qrow, 64);
            Op[(size_t)(q0 + qrow) * DD + q31]      = f0[r] * lv;
            Op[(size_t)(q0 + qrow) * DD + 32 + q31] = f1[r] * lv;
        }
    }
#undef KL
#undef VT
}

extern "C" void kernel_launch(void* const* d_in, const int* in_sizes, int n_in,
                              void* d_out, int out_size, void* d_ws, size_t ws_size,
                              hipStream_t stream) {
    const float* keys    = (const float*)d_in[0];
    const float* queries = (const float*)d_in[1];
    const float* values  = (const float*)d_in[2];
    float* out           = (float*)d_out;

    dim3 grid(512);           // 32 bh x 16 q-tiles (128 rows each)
    dim3 block(640, 1, 1);    // 8 consumer waves + 2 producer waves
    mha_fwd_kernel<<<grid, block, 0, stream>>>(keys, queries, values, out);
}

// Round 10
// 181.075 us; speedup vs baseline: 1.4750x; 1.4750x over previous
//
#include <hip/hip_runtime.h>

// Causal MHA fwd: B=2, N=2048, H=16, D=64. fp32 in / fp32 out.
// Tensors flat row-major (B*H, N, 64). Flash attention, 32x32 MFMA.
//
// Round 21 = Round 18 VERBATIM (verified correct: absmax 0.0234) with the
// single mechanical fix for its 4x regression:
//  - R18 failure mode: producer waves staged 64 f32 in registers at once
//    -> spill to scratch (VGPR=48, WRITE_SIZE 16->247MB, 204us).
//  - Fix: producers stage in 4 CHUNKS of 16 live registers each
//    (load 8 K-f32 + 8 V-f32, wait, pack, write LDS, next chunk).
//    Producer vmcnt stalls are free by design - they overlap consumer
//    compute across the barrier interval; chunking costs producers
//    nothing and caps their live-set at 16 regs.
//  - amdgpu_waves_per_eu(5,5): pin allocator at 5 waves/EU (cap ~102
//    VGPR, 2 blocks/CU). Consumers need ~90 (o=32, qf=16, sT=16 + addr);
//    producers ~30. R18's heuristic picked 48 and spilled; pin it.
//  - R20's 512-thread all-stage variant failed (absmax 0.34) despite
//    identical-on-paper math; reverted to the verified R18 structure.
// Structure (unchanged from R18): 512 blocks x (8 consumer + 2 producer)
// waves; consumers = 4 q-groups x 2 key-halves (exp2-direct softmax =>
// key-halves combine linearly; LDS-scratch combine at epilogue);
// itl = 2Tq + ((qw-kh)>>1), triangular mask iff (qw-kh) even;
// double-buffered LDS, 1 barrier/iter; pair-balanced T-map; bh=rb&31.

typedef short  short8v __attribute__((ext_vector_type(8)));
typedef float  float8v __attribute__((ext_vector_type(8)));
typedef float  f32x16  __attribute__((ext_vector_type(16)));

#define NQ 2048
#define DD 64
#define KT 64          // keys per iteration
#define KP 72          // K LDS row pitch (bf16 elts), 144B
#define VP 72          // V^T LDS row pitch

#define Z16 ((f32x16){0.f,0.f,0.f,0.f,0.f,0.f,0.f,0.f,0.f,0.f,0.f,0.f,0.f,0.f,0.f,0.f})
#define mfma32 __builtin_amdgcn_mfma_f32_32x32x16_bf16

union U4 { unsigned int u[4]; short8v s; };

// truncating pack: two f32 -> two bf16 (lo -> low half) — K/V staging
static __device__ __forceinline__ unsigned int pktr(float lo, float hi) {
    return __builtin_amdgcn_perm(__builtin_bit_cast(unsigned int, hi),
                                 __builtin_bit_cast(unsigned int, lo),
                                 0x07060302);
}
// round-half-up pack — used for Q (once per wave)
static __device__ __forceinline__ unsigned int pkrn(float lo, float hi) {
    unsigned int a = __builtin_bit_cast(unsigned int, hi) + 0x8000u;
    unsigned int b = __builtin_bit_cast(unsigned int, lo) + 0x8000u;
    return __builtin_amdgcn_perm(a, b, 0x07060302);
}
// RNE pack via HW instruction (P values)
static __device__ __forceinline__ unsigned int cvtpk(float lo, float hi) {
    unsigned int d;
    asm("v_cvt_pk_bf16_f32 %0, %1, %2" : "=v"(d) : "v"(lo), "v"(hi));
    return d;
}
// raw HW exp2 (no OCML guard); exp2(-3e38) = 0 handles the causal mask
static __device__ __forceinline__ float fexp2(float x) {
    float y;
    asm("v_exp_f32 %0, %1" : "=v"(y) : "v"(x));
    return y;
}

// Build one PA fragment (A-operand slice: P[q][16s'+8h+j], j=0..7)
// from sT regs B..B+7. After swap: P0,P1,P2,P3 = words w0..w3. (verified R16)
#define MK_PA(dst, S, B)                                                     \
    {                                                                        \
        unsigned int P0 = cvtpk(S[(B) + 0], S[(B) + 1]);                     \
        unsigned int P1 = cvtpk(S[(B) + 2], S[(B) + 3]);                     \
        unsigned int P2 = cvtpk(S[(B) + 4], S[(B) + 5]);                     \
        unsigned int P3 = cvtpk(S[(B) + 6], S[(B) + 7]);                     \
        asm("v_permlane32_swap_b32 %0, %1" : "+v"(P0), "+v"(P2));            \
        asm("v_permlane32_swap_b32 %0, %1" : "+v"(P1), "+v"(P3));            \
        U4 w_;                                                               \
        w_.u[0] = P0; w_.u[1] = P1; w_.u[2] = P2; w_.u[3] = P3;              \
        dst = w_.s;                                                          \
    }

// Producer chunked staging: 4 chunks x (16 K rows + 16 V keys), 16 live
// regs per chunk. Roles (128 producer lanes, pt = t-512):
//   K: row = c*16 + (pt>>3), cols (pt&7)*8 .. +7   (8 f32, coalesced)
//   V: d = pt&63, keys c*16 + ((pt>>6)&1)*8 .. +7  (8 f32)
#define STAGE_TILE(kbase, kdst, vdst)                                        \
    {                                                                        \
        _Pragma("unroll")                                                    \
        for (int c = 0; c < 4; ++c) {                                        \
            float8v ka = *(const float8v*)(Kp + (size_t)((kbase) + c * 16 + pkr) * DD + pkc); \
            float vr[8];                                                     \
            _Pragma("unroll")                                                \
            for (int i = 0; i < 8; ++i)                                      \
                vr[i] = Vp[(size_t)((kbase) + c * 16 + pvk + i) * DD + pvd]; \
            U4 wk, wv;                                                       \
            _Pragma("unroll")                                                \
            for (int i = 0; i < 4; ++i) {                                    \
                wk.u[i] = pktr(ka[2 * i], ka[2 * i + 1]);                    \
                wv.u[i] = pktr(vr[2 * i], vr[2 * i + 1]);                    \
            }                                                                \
            *(short8v*)&(kdst)[(c * 16 + pkr) * KP + pkc]   = wk.s;          \
            *(short8v*)&(vdst)[pvd * VP + c * 16 + pvk]     = wv.s;          \
        }                                                                    \
    }

__global__ __launch_bounds__(640, 5) __attribute__((amdgpu_waves_per_eu(5, 5)))
void mha_fwd_kernel(
    const float* __restrict__ Kg,
    const float* __restrict__ Qg,
    const float* __restrict__ Vg,
    float* __restrict__ Og)
{
    // [Klds buf0|buf1][Vt buf0|buf1], 36864 B; reused as f32 scratch for
    // the kh-combine epilogue (needs 33788 B).
    __shared__ __align__(16) unsigned short SM[2 * KT * KP + 2 * DD * VP];
#define KL(c) (&SM[(c) * (KT * KP)])
#define VT(c) (&SM[2 * (KT * KP) + (c) * (DD * VP)])

    const int t    = threadIdx.x;
    const int lane = t & 63;
    const int wave = t >> 6;       // 0..9
    const int q31  = lane & 31;
    const int h    = lane >> 5;

    // 512 blocks: b&255 -> (bh, jj); b>>8 picks heavy (15-jj) vs light (jj)
    // q-tile. CU gets blocks b and b+256: iteration sum = 36 (balanced).
    const int b   = blockIdx.x;
    const int rb  = b & 255;
    const int bh  = rb & 31;
    const int jj  = rb >> 5;                   // 0..7
    const int Tq  = (b >> 8) ? jj : (15 - jj); // q-tile index, 128 rows
    const int nt  = 2 * Tq + 2;                // block k-iterations

    const bool producer = (wave >= 8);
    const int  qw = wave & 3;                  // consumer q-group
    const int  kh = (wave >> 2) & 1;           // consumer key-half
    const int  q0 = Tq * 128 + qw * 32;        // consumer's 32 q rows
    // last compute iteration; triangular diagonal iff (qw-kh) even
    const int  itl  = producer ? -1 : (2 * Tq + ((qw - kh) >> 1));
    const bool hasd = !producer && (((qw - kh) & 1) == 0);

    const size_t base = (size_t)bh * NQ * DD;
    const float* Qp = Qg + base;
    const float* Kp = Kg + base;
    const float* Vp = Vg + base;
    float*       Op = Og + base;

    const float sscale = 0.125f * 1.4426950408889634f;  // 1/sqrt(64)*log2(e)

    // producer chunk roles (valid only for producer waves)
    const int pt  = t - 512;
    const int pkr = pt >> 3;                   // K row within chunk, 0..15
    const int pkc = (pt & 7) * 8;              // K col group
    const int pvd = pt & 63;                   // V d-row
    const int pvk = ((pt >> 6) & 1) * 8;       // V key offset within chunk

    // ---- consumer: Q fragments (B-operand), scale folded, RNE pack ----
    short8v qf[4];
    if (!producer) {
#pragma unroll
        for (int s = 0; s < 4; ++s) {
            float8v a = *(const float8v*)(Qp + (size_t)(q0 + q31) * DD + s * 16 + h * 8);
            U4 w;
#pragma unroll
            for (int i = 0; i < 4; ++i)
                w.u[i] = pkrn(a[2 * i] * sscale, a[2 * i + 1] * sscale);
            qf[s] = w.s;
        }
    }

    float  l_i = 0.0f;
    f32x16 o0 = Z16, o1 = Z16;

    // ---- prologue: producers stage tile 0 into buffer 0 (chunked) ----
    if (producer) {
        STAGE_TILE(0, KL(0), VT(0));
    }
    __syncthreads();

    for (int it = 0; it < nt; ++it) {
        const int cur = it & 1;

        if (producer) {
            // stage tile it+1 into buf[cur^1]; chunked, 16 live regs;
            // vmcnt stalls overlap consumer compute in this interval
            if (it + 1 < nt) {
                const int nkb = (it + 1) * KT;
                STAGE_TILE(nkb, KL(cur ^ 1), VT(cur ^ 1));
            }
        } else if (it <= itl) {
            // ---- consumer: one 32-key half-tile ----
            __builtin_amdgcn_s_setprio(1);

            f32x16 sT = Z16;
#pragma unroll
            for (int s = 0; s < 4; ++s) {
                short8v kf = *(const short8v*)&KL(cur)[(kh * 32 + q31) * KP + s * 16 + h * 8];
                sT = mfma32(kf, qf[s], sT, 0, 0, 0);
            }

            if (hasd && it == itl) {
#pragma unroll
                for (int r = 0; r < 16; ++r) {
                    const int kcst = (r & 3) + 8 * (r >> 2);
                    if (kcst + 4 * h > q31) sT[r] = -3.0e38f;
                }
            }

#pragma unroll
            for (int r = 0; r < 16; ++r) sT[r] = fexp2(sT[r]);
            l_i += (((sT[0] + sT[1]) + (sT[2] + sT[3])) +
                    ((sT[4] + sT[5]) + (sT[6] + sT[7]))) +
                   (((sT[8] + sT[9]) + (sT[10] + sT[11])) +
                    ((sT[12] + sT[13]) + (sT[14] + sT[15])));

            short8v pa0, pa1;
            MK_PA(pa0, sT, 0);
            MK_PA(pa1, sT, 8);

            const unsigned short* vb = VT(cur);
            short8v v00 = *(const short8v*)&vb[q31 * VP        + (2 * kh)     * 16 + h * 8];
            short8v v01 = *(const short8v*)&vb[q31 * VP        + (2 * kh + 1) * 16 + h * 8];
            short8v v10 = *(const short8v*)&vb[(32 + q31) * VP + (2 * kh)     * 16 + h * 8];
            short8v v11 = *(const short8v*)&vb[(32 + q31) * VP + (2 * kh + 1) * 16 + h * 8];
            o0 = mfma32(pa0, v00, o0, 0, 0, 0);
            o0 = mfma32(pa1, v01, o0, 0, 0, 0);
            o1 = mfma32(pa0, v10, o1, 0, 0, 0);
            o1 = mfma32(pa1, v11, o1, 0, 0, 0);

            __builtin_amdgcn_s_setprio(0);
        }

        __syncthreads();  // buf[cur^1] staged; buf[cur] reads drained
    }

    // ---- epilogue: combine kh halves via LDS (linear: exp2-direct) ----
    const float rs0 = l_i + __shfl_xor(l_i, 32);
    float* smf = (float*)SM;
    if (!producer && kh == 1) {
        float* dst = smf + (qw * 64 + lane) * 33;
#pragma unroll
        for (int r = 0; r < 16; ++r) { dst[r] = o0[r]; dst[16 + r] = o1[r]; }
        dst[32] = rs0;
    }
    __syncthreads();
    if (!producer && kh == 0) {
        const float* src = smf + (qw * 64 + lane) * 33;
        const float rs = rs0 + src[32];
        f32x16 f0 = o0, f1 = o1;
#pragma unroll
        for (int r = 0; r < 16; ++r) { f0[r] += src[r]; f1[r] += src[16 + r]; }
        const float rinv = 1.0f / rs;
#pragma unroll
        for (int r = 0; r < 16; ++r) {
            const int   qrow = (r & 3) + 8 * (r >> 2) + 4 * h;
            const float lv   = __shfl(rinv, qrow, 64);
            Op[(size_t)(q0 + qrow) * DD + q31]      = f0[r] * lv;
            Op[(size_t)(q0 + qrow) * DD + 32 + q31] = f1[r] * lv;
        }
    }
#undef KL
#undef VT
}

extern "C" void kernel_launch(void* const* d_in, const int* in_sizes, int n_in,
                              void* d_out, int out_size, void* d_ws, size_t ws_size,
                              hipStream_t stream) {
    const float* keys    = (const float*)d_in[0];
    const float* queries = (const float*)d_in[1];
    const float* values  = (const float*)d_in[2];
    float* out           = (float*)d_out;

    dim3 grid(512);           // 32 bh x 16 q-tiles (128 rows each)
    dim3 block(640, 1, 1);    // 8 consumer waves + 2 producer waves
    mha_fwd_kernel<<<grid, block, 0, stream>>>(keys, queries, values, out);
}

// Round 11
// 118.959 us; speedup vs baseline: 2.2452x; 1.5222x over previous
//
#include <hip/hip_runtime.h>

// Causal MHA fwd: B=2, N=2048, H=16, D=64. fp32 in / fp32 out.
// Tensors flat row-major (B*H, N, 64). Flash attention, 32x32 MFMA.
//
// Round 22 = Round 17 VERBATIM (best verified: 48us, absmax 0.0234) with
// the staged loads issued via VOLATILE INLINE ASM:
//  - Proven defect: allocator sinks staged loads to the pack point
//    (R16/R17 VGPR 72/76 < persistent(64)+staged(32) regs), serializing
//    an L2/L3 round-trip (~300-500cy) before every barrier.
//    sched_barrier(0) can't stop cross-BB sinking (R17). Registers-as-
//    home via producer waves spilled twice (R18: 247MB, R21: 37MB writes).
//  - Fix: volatile asm global_load_dwordx4 (K) + 16x global_load_dword
//    with offset:N immediates (V, one base pointer) at the TOP of the
//    iteration; volatile order pins the issue point. A s_waitcnt vmcnt(0)
//    asm tying all 20 dest regs ("+v") fences the packs at the bottom.
//    Load latency now deterministically overlaps the compute phase.
//  - Staged values/addresses/packs/LDS layout/compute/mask/epilogue are
//    bit-identical to R17; only load mechanics changed.
//  - Confirmation signals: VGPR ~105-135 (forced live), WRITE_SIZE stays
//    16.4MB (no spill), absmax 0.0234 exactly.
// Structure (R17): 512 blocks x 4 waves, 32 q-rows/wave 32x32 MFMA,
// 128-row q-tiles, pair-balanced T-map, double-buffered LDS (KP/VP=72,
// 0 bank conflicts), 1 barrier/iter, exp2-direct softmax (raw v_exp_f32),
// tree-reduced l, MK_PA permlane P-transform, diagonal tile1 skip.

typedef short  short8v __attribute__((ext_vector_type(8)));
typedef float  float4v __attribute__((ext_vector_type(4)));
typedef float  float8v __attribute__((ext_vector_type(8)));
typedef float  f32x16  __attribute__((ext_vector_type(16)));

#define NQ 2048
#define DD 64
#define KT 64          // keys per iteration
#define KP 72          // K LDS row pitch (bf16 elts), 144B
#define VP 72          // V^T LDS row pitch

#define Z16 ((f32x16){0.f,0.f,0.f,0.f,0.f,0.f,0.f,0.f,0.f,0.f,0.f,0.f,0.f,0.f,0.f,0.f})
#define mfma32 __builtin_amdgcn_mfma_f32_32x32x16_bf16

union U4 { unsigned int u[4]; short8v s; };

// truncating pack: two f32 -> two bf16 (lo -> low half) — K/V staging
static __device__ __forceinline__ unsigned int pktr(float lo, float hi) {
    return __builtin_amdgcn_perm(__builtin_bit_cast(unsigned int, hi),
                                 __builtin_bit_cast(unsigned int, lo),
                                 0x07060302);
}
// round-half-up pack — used for Q (once per wave)
static __device__ __forceinline__ unsigned int pkrn(float lo, float hi) {
    unsigned int a = __builtin_bit_cast(unsigned int, hi) + 0x8000u;
    unsigned int b = __builtin_bit_cast(unsigned int, lo) + 0x8000u;
    return __builtin_amdgcn_perm(a, b, 0x07060302);
}
// RNE pack via HW instruction (P values)
static __device__ __forceinline__ unsigned int cvtpk(float lo, float hi) {
    unsigned int d;
    asm("v_cvt_pk_bf16_f32 %0, %1, %2" : "=v"(d) : "v"(lo), "v"(hi));
    return d;
}
// raw HW exp2 (no OCML guard); exp2(-3e38) = 0 handles the causal mask
static __device__ __forceinline__ float fexp2(float x) {
    float y;
    asm("v_exp_f32 %0, %1" : "=v"(y) : "v"(x));
    return y;
}

// pinned-issue loads: volatile asm cannot be sunk or reordered
#define GLD4(dst, base, imm)                                                  \
    asm volatile("global_load_dwordx4 %0, %1, off offset:" #imm               \
                 : "=v"(dst) : "v"(base))
#define GLDW(dst, base, imm)                                                  \
    asm volatile("global_load_dword %0, %1, off offset:" #imm                 \
                 : "=v"(dst) : "v"(base))

// Build one PA fragment (A-operand slice: P[q][16s'+8h+j], j=0..7)
// from sT regs B..B+7. After swap: P0,P1,P2,P3 = words w0..w3. (verified R16)
#define MK_PA(dst, S, B)                                                     \
    {                                                                        \
        unsigned int P0 = cvtpk(S[(B) + 0], S[(B) + 1]);                     \
        unsigned int P1 = cvtpk(S[(B) + 2], S[(B) + 3]);                     \
        unsigned int P2 = cvtpk(S[(B) + 4], S[(B) + 5]);                     \
        unsigned int P3 = cvtpk(S[(B) + 6], S[(B) + 7]);                     \
        asm("v_permlane32_swap_b32 %0, %1" : "+v"(P0), "+v"(P2));            \
        asm("v_permlane32_swap_b32 %0, %1" : "+v"(P1), "+v"(P3));            \
        U4 w_;                                                               \
        w_.u[0] = P0; w_.u[1] = P1; w_.u[2] = P2; w_.u[3] = P3;              \
        dst = w_.s;                                                          \
    }

#define VF(td, s) (*(const short8v*)&Vt[cur][((td) * 32 + q31) * VP + (s) * 16 + h * 8])

__global__ __launch_bounds__(256, 2) void mha_fwd_kernel(
    const float* __restrict__ Kg,
    const float* __restrict__ Qg,
    const float* __restrict__ Vg,
    float* __restrict__ Og)
{
    __shared__ __align__(16) float          KldsPad[1];  // keep layout simple
    __shared__ __align__(16) unsigned short Klds[2][KT * KP];  // 2 x 9216 B
    __shared__ __align__(16) unsigned short Vt[2][DD * VP];    // 2 x 9216 B
    (void)KldsPad;

    const int t    = threadIdx.x;
    const int lane = t & 63;
    const int wave = t >> 6;       // 0..3
    const int q31  = lane & 31;
    const int h    = lane >> 5;

    // 512 blocks: b&255 -> (bh, jj); b>>8 picks heavy (15-jj) vs light (jj)
    // q-tile. CU gets blocks b and b+256: iteration sum = 34 (balanced).
    const int b   = blockIdx.x;
    const int rb  = b & 255;
    const int bh  = rb & 31;
    const int jj  = rb >> 5;                   // 0..7
    const int Tq  = (b >> 8) ? jj : (15 - jj); // q-tile index, 128 rows
    const int nt  = 2 * Tq + 2;                // block k-iterations
    const int q0  = Tq * 128 + wave * 32;      // wave's 32 q rows
    const int itl = 2 * Tq + (wave >> 1);      // wave's diagonal iteration

    const size_t base = (size_t)bh * NQ * DD;
    const float* Qp = Qg + base;
    const float* Kp = Kg + base;
    const float* Vp = Vg + base;
    float*       Op = Og + base;

    const float sscale = 0.125f * 1.4426950408889634f;  // 1/sqrt(64)*log2(e)

    // staging roles (256 threads) — fully coalesced (verbatim R17):
    const int kr = t >> 3, kc = (t & 7) * 8;   // K: rows kr, kr+32
    const int vd = t & 63, vg = (t >> 6) * 16; // V^T: row vd, keys vg..vg+15

    // ---- Q fragments (B-operand): lane holds Q[q0+q31][s*16+h*8+0..7] ----
    short8v qf[4];
#pragma unroll
    for (int s = 0; s < 4; ++s) {
        float8v a = *(const float8v*)(Qp + (size_t)(q0 + q31) * DD + s * 16 + h * 8);
        U4 w;
#pragma unroll
        for (int i = 0; i < 4; ++i)
            w.u[i] = pkrn(a[2 * i] * sscale, a[2 * i + 1] * sscale);
        qf[s] = w.s;
    }

    float  l_i = 0.0f;
    f32x16 o0 = Z16, o1 = Z16;

    // ---- prologue: stage tile 0 into buffer 0 (plain loads, once) ----
    {
        float8v pka0 = *(const float8v*)(Kp + (size_t)kr * DD + kc);
        float8v pka1 = *(const float8v*)(Kp + (size_t)(kr + 32) * DD + kc);
        float pvr[16];
#pragma unroll
        for (int i = 0; i < 16; ++i)
            pvr[i] = Vp[(size_t)(vg + i) * DD + vd];
        U4 w0, w1, wv0, wv1;
#pragma unroll
        for (int i = 0; i < 4; ++i) {
            w0.u[i]  = pktr(pka0[2 * i], pka0[2 * i + 1]);
            w1.u[i]  = pktr(pka1[2 * i], pka1[2 * i + 1]);
            wv0.u[i] = pktr(pvr[2 * i], pvr[2 * i + 1]);
            wv1.u[i] = pktr(pvr[8 + 2 * i], pvr[9 + 2 * i]);
        }
        *(short8v*)&Klds[0][kr * KP + kc]        = w0.s;
        *(short8v*)&Klds[0][(kr + 32) * KP + kc] = w1.s;
        *(short8v*)&Vt[0][vd * VP + vg]          = wv0.s;
        *(short8v*)&Vt[0][vd * VP + vg + 8]      = wv1.s;
    }
    __syncthreads();

    for (int it = 0; it < nt; ++it) {
        const int  cur = it & 1;
        const bool stg = (it + 1 < nt);

        // ---- PINNED issue of next-tile loads (volatile asm: cannot sink).
        //      Latency overlaps the whole compute phase below. ----
        float4v k0a, k0b, k1a, k1b;
        float v00, v01, v02, v03, v04, v05, v06, v07;
        float v08, v09, v10, v11, v12, v13, v14, v15;
        if (stg) {
            const int nkb = (it + 1) * KT;
            const float* kp0 = Kp + (size_t)(nkb + kr) * DD + kc;
            const float* kp1 = Kp + (size_t)(nkb + kr + 32) * DD + kc;
            const float* vp0 = Vp + (size_t)(nkb + vg) * DD + vd;
            GLD4(k0a, kp0, 0);  GLD4(k0b, kp0, 16);
            GLD4(k1a, kp1, 0);  GLD4(k1b, kp1, 16);
            GLDW(v00, vp0, 0);    GLDW(v01, vp0, 256);
            GLDW(v02, vp0, 512);  GLDW(v03, vp0, 768);
            GLDW(v04, vp0, 1024); GLDW(v05, vp0, 1280);
            GLDW(v06, vp0, 1536); GLDW(v07, vp0, 1792);
            GLDW(v08, vp0, 2048); GLDW(v09, vp0, 2304);
            GLDW(v10, vp0, 2560); GLDW(v11, vp0, 2816);
            GLDW(v12, vp0, 3072); GLDW(v13, vp0, 3328);
            GLDW(v14, vp0, 3584); GLDW(v15, vp0, 3840);
        }

        // ---- compute (wave drops out past its diagonal) — R17 verbatim ----
        if (it <= itl) {
            __builtin_amdgcn_s_setprio(1);
            const bool diag = (it == itl);
            const bool do1  = (!diag) || (wave & 1);  // tile1 live?

            short8v pa0, pa1, pa2, pa3;

            // tile 0: keys it*64 + 0..31
            {
                f32x16 sT = Z16;
#pragma unroll
                for (int s = 0; s < 4; ++s) {
                    short8v kf = *(const short8v*)&Klds[cur][q31 * KP + s * 16 + h * 8];
                    sT = mfma32(kf, qf[s], sT, 0, 0, 0);
                }
                if (diag && !(wave & 1)) {
#pragma unroll
                    for (int r = 0; r < 16; ++r) {
                        const int kcst = (r & 3) + 8 * (r >> 2);
                        if (kcst + 4 * h > q31) sT[r] = -3.0e38f;
                    }
                }
#pragma unroll
                for (int r = 0; r < 16; ++r) sT[r] = fexp2(sT[r]);
                l_i += (((sT[0] + sT[1]) + (sT[2] + sT[3])) +
                        ((sT[4] + sT[5]) + (sT[6] + sT[7]))) +
                       (((sT[8] + sT[9]) + (sT[10] + sT[11])) +
                        ((sT[12] + sT[13]) + (sT[14] + sT[15])));
                MK_PA(pa0, sT, 0);
                MK_PA(pa1, sT, 8);
            }
            o0 = mfma32(pa0, VF(0, 0), o0, 0, 0, 0);
            o1 = mfma32(pa0, VF(1, 0), o1, 0, 0, 0);
            o0 = mfma32(pa1, VF(0, 1), o0, 0, 0, 0);
            o1 = mfma32(pa1, VF(1, 1), o1, 0, 0, 0);

            // tile 1: keys it*64 + 32..63 (skipped when fully masked)
            if (do1) {
                f32x16 sU = Z16;
#pragma unroll
                for (int s = 0; s < 4; ++s) {
                    short8v kf = *(const short8v*)&Klds[cur][(32 + q31) * KP + s * 16 + h * 8];
                    sU = mfma32(kf, qf[s], sU, 0, 0, 0);
                }
                if (diag && (wave & 1)) {
#pragma unroll
                    for (int r = 0; r < 16; ++r) {
                        const int kcst = (r & 3) + 8 * (r >> 2);
                        if (kcst + 4 * h > q31) sU[r] = -3.0e38f;
                    }
                }
#pragma unroll
                for (int r = 0; r < 16; ++r) sU[r] = fexp2(sU[r]);
                l_i += (((sU[0] + sU[1]) + (sU[2] + sU[3])) +
                        ((sU[4] + sU[5]) + (sU[6] + sU[7]))) +
                       (((sU[8] + sU[9]) + (sU[10] + sU[11])) +
                        ((sU[12] + sU[13]) + (sU[14] + sU[15])));
                MK_PA(pa2, sU, 0);
                MK_PA(pa3, sU, 8);
                o0 = mfma32(pa2, VF(0, 2), o0, 0, 0, 0);
                o1 = mfma32(pa2, VF(1, 2), o1, 0, 0, 0);
                o0 = mfma32(pa3, VF(0, 3), o0, 0, 0, 0);
                o1 = mfma32(pa3, VF(1, 3), o1, 0, 0, 0);
            }
            __builtin_amdgcn_s_setprio(0);
        }

        // ---- fence: all pinned loads complete; then pack+write (R17) ----
        if (stg) {
            asm volatile("s_waitcnt vmcnt(0)"
                         : "+v"(k0a), "+v"(k0b), "+v"(k1a), "+v"(k1b),
                           "+v"(v00), "+v"(v01), "+v"(v02), "+v"(v03),
                           "+v"(v04), "+v"(v05), "+v"(v06), "+v"(v07),
                           "+v"(v08), "+v"(v09), "+v"(v10), "+v"(v11),
                           "+v"(v12), "+v"(v13), "+v"(v14), "+v"(v15));
            U4 w0, w1, wv0, wv1;
            w0.u[0] = pktr(k0a[0], k0a[1]);  w0.u[1] = pktr(k0a[2], k0a[3]);
            w0.u[2] = pktr(k0b[0], k0b[1]);  w0.u[3] = pktr(k0b[2], k0b[3]);
            w1.u[0] = pktr(k1a[0], k1a[1]);  w1.u[1] = pktr(k1a[2], k1a[3]);
            w1.u[2] = pktr(k1b[0], k1b[1]);  w1.u[3] = pktr(k1b[2], k1b[3]);
            wv0.u[0] = pktr(v00, v01); wv0.u[1] = pktr(v02, v03);
            wv0.u[2] = pktr(v04, v05); wv0.u[3] = pktr(v06, v07);
            wv1.u[0] = pktr(v08, v09); wv1.u[1] = pktr(v10, v11);
            wv1.u[2] = pktr(v12, v13); wv1.u[3] = pktr(v14, v15);
            *(short8v*)&Klds[cur ^ 1][kr * KP + kc]        = w0.s;
            *(short8v*)&Klds[cur ^ 1][(kr + 32) * KP + kc] = w1.s;
            *(short8v*)&Vt[cur ^ 1][vd * VP + vg]          = wv0.s;
            *(short8v*)&Vt[cur ^ 1][vd * VP + vg + 8]      = wv1.s;
        }

        __syncthreads();  // buf[cur^1] ready; buf[cur] reads drained
    }

    // ---- epilogue: l across lane-halves, broadcast 1/l by q-row, store ----
    const float rs   = l_i + __shfl_xor(l_i, 32);
    const float rinv = 1.0f / rs;
#pragma unroll
    for (int r = 0; r < 16; ++r) {
        const int   qrow = (r & 3) + 8 * (r >> 2) + 4 * h;
        const float lv   = __shfl(rinv, qrow, 64);
        Op[(size_t)(q0 + qrow) * DD + q31]      = o0[r] * lv;
        Op[(size_t)(q0 + qrow) * DD + 32 + q31] = o1[r] * lv;
    }
}

extern "C" void kernel_launch(void* const* d_in, const int* in_sizes, int n_in,
                              void* d_out, int out_size, void* d_ws, size_t ws_size,
                              hipStream_t stream) {
    const float* keys    = (const float*)d_in[0];
    const float* queries = (const float*)d_in[1];
    const float* values  = (const float*)d_in[2];
    float* out           = (float*)d_out;

    dim3 grid(512);           // 32 bh x 16 q-tiles (128 rows each)
    dim3 block(256, 1, 1);
    mha_fwd_kernel<<<grid, block, 0, stream>>>(keys, queries, values, out);
}